// Round 10
// baseline (35.579 us; speedup 1.0000x reference)
//
#include <hip/hip_runtime.h>
#include <hip/hip_bf16.h>

#define NB   32      // batch N
#define NRR  48      // rows NR
#define TT   2048    // temporal length T
#define DD   256     // d_model
#define QQ   32      // query points
#define ROWS (NB * NRR)   // 1536 total rows
#define NXCD 8
#define SLICE (TT * DD)   // floats per feature slice (524288 = 2 MiB)
#define PF_CH 2732        // prefetch floats per wave (192 waves/slice, 4-aligned)

typedef float f32x4 __attribute__((ext_vector_type(4)));

// R9 structure + linear L2/L3 prefetch of the feature slices.
// 3072 blocks x 128 threads (2 independent waves). Block b -> (row, half) with
// XCD swizzle (all blocks of one n-slice on one XCD). Each wave covers all 256
// channels as f32x4, computes the 16 tiny dots redundantly, owns 8 q points.
// NEW: the 192 waves of each n-slice cooperatively stream the whole 2 MiB
// slice SEQUENTIALLY via global_load_lds into a dummy LDS sink (never read,
// zero VGPR). This converts the compulsory HBM fetch of `features` from
// random 64B demand-gathers (~3-4 TB/s effective) into a linear stream
// (~6.3 TB/s); the gathers then hit warm L2/L3. Prefetch is issued after the
// pro/weight loads so the dot phase only waits vmcnt(11), and it drains under
// the butterfly+softmax VALU phase.
__global__ __launch_bounds__(128) void pd_kernel(
    const float* __restrict__ pro,     // (N, NR, D)
    const float* __restrict__ feat,    // (N, T, D)
    const float* __restrict__ sp,      // (N, NR, Q)
    const float* __restrict__ w_bo, const float* __restrict__ b_bo,
    const float* __restrict__ w_co, const float* __restrict__ b_co,
    const float* __restrict__ w_bw, const float* __restrict__ b_bw,
    const float* __restrict__ w_cw, const float* __restrict__ b_cw,
    float* __restrict__ out)           // (Q, ROWS, D)
{
    __shared__ char pf_sink[1024];     // 64 lanes x 16B; garbage, never read

    const int bid  = blockIdx.x;
    const int xcd  = bid & (NXCD - 1);       // hardware XCD
    const int t    = bid >> 3;               // 0..383 within XCD
    const int half = t & 1;                  // which 16-q half
    const int row  = xcd * (ROWS / NXCD) + (t >> 1);   // n in [4*xcd, 4*xcd+4)
    const int n    = row / NRR;
    const int v    = row % NRR;
    const int lane = threadIdx.x & 63;
    const int wv   = threadIdx.x >> 6;       // wave 0..1
    const int d4   = lane << 2;              // channel base (f32x4 per lane)
    const float inv_w = 1.0f / 2048.0f;

    // ---- issue the pro/weight loads FIRST (so dots wait only vmcnt(11)) ----
    const f32x4 pv = *reinterpret_cast<const f32x4*>(pro + (size_t)row * DD + d4);
    f32x4 wreg[16];
#pragma unroll
    for (int s = 0; s < 4; ++s) {
        wreg[s]      = *reinterpret_cast<const f32x4*>(w_bo + s * DD + d4);
        wreg[4 + s]  = *reinterpret_cast<const f32x4*>(w_co + s * DD + d4);
        wreg[8 + s]  = *reinterpret_cast<const f32x4*>(w_bw + s * DD + d4);
        wreg[12 + s] = *reinterpret_cast<const f32x4*>(w_cw + s * DD + d4);
    }

    // ---- linear prefetch of this wave's chunk of feature slice n ----
    const float* fnrow = feat + (size_t)n * SLICE;       // wave-uniform base
    {
        const int wslice = v * 4 + half * 2 + wv;        // 0..191 within slice
        const int base   = wslice * PF_CH + (lane << 2);
#pragma unroll
        for (int i = 0; i < 11; ++i) {
            int off = base + i * 256;                    // 64 lanes x 4 floats
            off = off > (SLICE - 4) ? (SLICE - 4) : off;
            __builtin_amdgcn_global_load_lds(
                (const __attribute__((address_space(1))) void*)(fnrow + off),
                (__attribute__((address_space(3))) void*)pf_sink,
                16, 0, 0);
        }
    }

    // ---- 16 dot products of pro[row,:] with the 4x4 weight rows ----
    float acc[16];
#pragma unroll
    for (int k = 0; k < 16; ++k)
        acc[k] = pv.x * wreg[k].x + pv.y * wreg[k].y
               + pv.z * wreg[k].z + pv.w * wreg[k].w;
    // 64-lane butterfly reduce; every lane ends with all 16 dot values.
#pragma unroll
    for (int st = 1; st < 64; st <<= 1) {
#pragma unroll
        for (int k = 0; k < 16; ++k)
            acc[k] += __shfl_xor(acc[k], st, 64);
    }

    float boff[4], coff[4], bw[4], cw[4];
#pragma unroll
    for (int s = 0; s < 4; ++s) {
        boff[s] = (acc[s]      + b_bo[s]) * inv_w;   // offset/WINDOW hoisted
        coff[s] = (acc[4 + s]  + b_co[s]) * inv_w;
        bw[s]   = acc[8 + s]  + b_bw[s];
        cw[s]   = acc[12 + s] + b_cw[s];
    }
    {   // softmax over s (max-subtracted), fold in the 0.5 row weight
        float mb = fmaxf(fmaxf(bw[0], bw[1]), fmaxf(bw[2], bw[3]));
        float mc = fmaxf(fmaxf(cw[0], cw[1]), fmaxf(cw[2], cw[3]));
        float sb = 0.f, sc = 0.f;
#pragma unroll
        for (int s = 0; s < 4; ++s) { bw[s] = expf(bw[s] - mb); sb += bw[s]; }
#pragma unroll
        for (int s = 0; s < 4; ++s) { cw[s] = expf(cw[s] - mc); sc += cw[s]; }
        const float rb = 0.5f / sb, rc = 0.5f / sc;
#pragma unroll
        for (int s = 0; s < 4; ++s) { bw[s] *= rb; cw[s] *= rc; }
    }

    // ---- gather + mix: this wave owns q = 16*half + 8*wv + j, j=0..7 ----
    const float* spr   = sp + (size_t)row * QQ;
    const int    qbase = (half << 4) + (wv << 3);

#pragma unroll
    for (int j = 0; j < 8; ++j) {
        const int   q     = qbase + j;
        const bool  isB   = (q < 4);             // wave-uniform
        const float point = spr[q];

        int   idx[8];
        float cc[8];
#pragma unroll
        for (int s = 0; s < 4; ++s) {
            const float off = isB ? boff[s] : coff[s];
            const float loc = fminf(fmaxf(point + off, 0.f), 1.f);
            const float px  = loc * (float)TT - 0.5f;
            const float x0f = floorf(px);
            const float w1  = px - x0f;          // right-neighbor weight
            const int   x0  = (int)x0f;          // in [-1, 2047]
            const int   x0c = x0 < 0 ? 0 : x0;
            const int   x1c = x0 + 1 > TT - 1 ? TT - 1 : x0 + 1;
            const float wgt = isB ? bw[s] : cw[s];
            cc[2 * s]     = (x0 >= 0)     ? wgt * (1.f - w1) : 0.f;
            cc[2 * s + 1] = (x0 + 1 < TT) ? wgt * w1         : 0.f;
            idx[2 * s]     = __builtin_amdgcn_readfirstlane(x0c) * DD;
            idx[2 * s + 1] = __builtin_amdgcn_readfirstlane(x1c) * DD;
        }

        f32x4 gv[8];
#pragma unroll
        for (int k = 0; k < 8; ++k)
            gv[k] = *reinterpret_cast<const f32x4*>(fnrow + idx[k] + d4);

        // Pin: all 8 loads issued before any consumer (MLP=8).
        __builtin_amdgcn_sched_barrier(0);

        f32x4 o = {0.f, 0.f, 0.f, 0.f};
#pragma unroll
        for (int k = 0; k < 8; ++k)
            o += cc[k] * gv[k];

        __builtin_nontemporal_store(o,
            reinterpret_cast<f32x4*>(out + ((size_t)q * ROWS + row) * DD + d4));
    }
}

extern "C" void kernel_launch(void* const* d_in, const int* in_sizes, int n_in,
                              void* d_out, int out_size, void* d_ws, size_t ws_size,
                              hipStream_t stream) {
    const float* pro  = (const float*)d_in[0];
    const float* feat = (const float*)d_in[1];
    const float* sp   = (const float*)d_in[2];
    const float* w_bo = (const float*)d_in[3];
    const float* b_bo = (const float*)d_in[4];
    const float* w_co = (const float*)d_in[5];
    const float* b_co = (const float*)d_in[6];
    const float* w_bw = (const float*)d_in[7];
    const float* b_bw = (const float*)d_in[8];
    const float* w_cw = (const float*)d_in[9];
    const float* b_cw = (const float*)d_in[10];
    float* out = (float*)d_out;

    pd_kernel<<<ROWS * 2, 128, 0, stream>>>(
        pro, feat, sp, w_bo, b_bo, w_co, b_co, w_bw, b_bw, w_cw, b_cw, out);
}

// Round 11
// 33.586 us; speedup vs baseline: 1.0593x; 1.0593x over previous
//
#include <hip/hip_runtime.h>
#include <hip/hip_bf16.h>

#define NB   32      // batch N
#define NRR  48      // rows NR
#define TT   2048    // temporal length T
#define DD   256     // d_model
#define QQ   32      // query points
#define ROWS (NB * NRR)   // 1536 total rows
#define NXCD 8

typedef float f32x4 __attribute__((ext_vector_type(4)));

// Two-phase L2-fit variant on the R9 skeleton (VGPR-40 inner structure).
// 1536 blocks x 128 threads (2 independent waves, no syncthreads).
// Block b -> xcd = b&7, t = b>>3 in [0,192): half = t&1, rr = (t>>1)%48,
// g = (t>>1)/48. Phase p in {0,1}: n = 16p + 2*xcd + g.
// => during phase 0 each XCD gathers from only 2 slices (4 MiB = its L2);
// phase 1 moves to the other 16 slices. This halves the per-XCD live
// working set vs R9 (8 MiB, ~50% L2 miss -> L3/fabric service wall).
// Unlike R7/R8: full grid width, no min-occupancy bound, single-q 8-load
// bursts (32 VGPR live) so the phase loop cannot spill.
__global__ __launch_bounds__(128) void pd_kernel(
    const float* __restrict__ pro,     // (N, NR, D)
    const float* __restrict__ feat,    // (N, T, D)
    const float* __restrict__ sp,      // (N, NR, Q)
    const float* __restrict__ w_bo, const float* __restrict__ b_bo,
    const float* __restrict__ w_co, const float* __restrict__ b_co,
    const float* __restrict__ w_bw, const float* __restrict__ b_bw,
    const float* __restrict__ w_cw, const float* __restrict__ b_cw,
    float* __restrict__ out)           // (Q, ROWS, D)
{
    const int bid  = blockIdx.x;
    const int xcd  = bid & (NXCD - 1);       // hardware XCD
    const int t    = bid >> 3;               // 0..191 within XCD
    const int half = t & 1;                  // which 16-q half of the row
    const int v2   = t >> 1;                 // 0..95
    const int rr   = v2 % NRR;               // row within slice
    const int g    = v2 / NRR;               // 0/1: slice within the pair
    const int lane = threadIdx.x & 63;
    const int wv   = threadIdx.x >> 6;       // wave 0..1
    const int d4   = lane << 2;              // channel base (f32x4 per lane)
    const float inv_w = 1.0f / 2048.0f;
    const int qbase = (half << 4) + (wv << 3);

#pragma unroll 1   // phases must execute sequentially (that IS the locality)
    for (int p = 0; p < 2; ++p) {
        const int n   = 16 * p + 2 * xcd + g;    // phase-local slice
        const int row = n * NRR + rr;

        // ---- 16 dot products of pro[row,:] with the 4x4 weight rows ----
        const f32x4 pv = *reinterpret_cast<const f32x4*>(pro + (size_t)row * DD + d4);

        float acc[16];
#pragma unroll
        for (int s = 0; s < 4; ++s) {
            f32x4 w;
            w = *reinterpret_cast<const f32x4*>(w_bo + s * DD + d4);
            acc[s]      = pv.x * w.x + pv.y * w.y + pv.z * w.z + pv.w * w.w;
            w = *reinterpret_cast<const f32x4*>(w_co + s * DD + d4);
            acc[4 + s]  = pv.x * w.x + pv.y * w.y + pv.z * w.z + pv.w * w.w;
            w = *reinterpret_cast<const f32x4*>(w_bw + s * DD + d4);
            acc[8 + s]  = pv.x * w.x + pv.y * w.y + pv.z * w.z + pv.w * w.w;
            w = *reinterpret_cast<const f32x4*>(w_cw + s * DD + d4);
            acc[12 + s] = pv.x * w.x + pv.y * w.y + pv.z * w.z + pv.w * w.w;
        }
        // 64-lane butterfly reduce; every lane ends with all 16 dot values.
#pragma unroll
        for (int st = 1; st < 64; st <<= 1) {
#pragma unroll
            for (int k = 0; k < 16; ++k)
                acc[k] += __shfl_xor(acc[k], st, 64);
        }

        float boff[4], coff[4], bw[4], cw[4];
#pragma unroll
        for (int s = 0; s < 4; ++s) {
            boff[s] = (acc[s]      + b_bo[s]) * inv_w;   // offset/WINDOW hoisted
            coff[s] = (acc[4 + s]  + b_co[s]) * inv_w;
            bw[s]   = acc[8 + s]  + b_bw[s];
            cw[s]   = acc[12 + s] + b_cw[s];
        }
        {   // softmax over s (max-subtracted), fold in the 0.5 row weight
            float mb = fmaxf(fmaxf(bw[0], bw[1]), fmaxf(bw[2], bw[3]));
            float mc = fmaxf(fmaxf(cw[0], cw[1]), fmaxf(cw[2], cw[3]));
            float sb = 0.f, sc = 0.f;
#pragma unroll
            for (int s = 0; s < 4; ++s) { bw[s] = expf(bw[s] - mb); sb += bw[s]; }
#pragma unroll
            for (int s = 0; s < 4; ++s) { cw[s] = expf(cw[s] - mc); sc += cw[s]; }
            const float rb = 0.5f / sb, rc = 0.5f / sc;
#pragma unroll
            for (int s = 0; s < 4; ++s) { bw[s] *= rb; cw[s] *= rc; }
        }

        // ---- gather + mix: this wave owns q = qbase + j, j=0..7 ----
        const float* fnrow = feat + (size_t)n * (TT * DD);   // wave-uniform base
        const float* spr   = sp + (size_t)row * QQ;

#pragma unroll
        for (int j = 0; j < 8; ++j) {
            const int   q     = qbase + j;
            const bool  isB   = (q < 4);             // wave-uniform
            const float point = spr[q];

            int   idx[8];
            float cc[8];
#pragma unroll
            for (int s = 0; s < 4; ++s) {
                const float off = isB ? boff[s] : coff[s];
                const float loc = fminf(fmaxf(point + off, 0.f), 1.f);
                const float px  = loc * (float)TT - 0.5f;
                const float x0f = floorf(px);
                const float w1  = px - x0f;          // right-neighbor weight
                const int   x0  = (int)x0f;          // in [-1, 2047]
                const int   x0c = x0 < 0 ? 0 : x0;
                const int   x1c = x0 + 1 > TT - 1 ? TT - 1 : x0 + 1;
                const float wgt = isB ? bw[s] : cw[s];
                cc[2 * s]     = (x0 >= 0)     ? wgt * (1.f - w1) : 0.f;
                cc[2 * s + 1] = (x0 + 1 < TT) ? wgt * w1         : 0.f;
                idx[2 * s]     = __builtin_amdgcn_readfirstlane(x0c) * DD;
                idx[2 * s + 1] = __builtin_amdgcn_readfirstlane(x1c) * DD;
            }

            f32x4 gv[8];
#pragma unroll
            for (int k = 0; k < 8; ++k)
                gv[k] = *reinterpret_cast<const f32x4*>(fnrow + idx[k] + d4);

            // Pin: all 8 loads issued before any consumer (MLP=8).
            __builtin_amdgcn_sched_barrier(0);

            f32x4 o = {0.f, 0.f, 0.f, 0.f};
#pragma unroll
            for (int k = 0; k < 8; ++k)
                o += cc[k] * gv[k];

            __builtin_nontemporal_store(o,
                reinterpret_cast<f32x4*>(out + ((size_t)q * ROWS + row) * DD + d4));
        }
    }
}

extern "C" void kernel_launch(void* const* d_in, const int* in_sizes, int n_in,
                              void* d_out, int out_size, void* d_ws, size_t ws_size,
                              hipStream_t stream) {
    const float* pro  = (const float*)d_in[0];
    const float* feat = (const float*)d_in[1];
    const float* sp   = (const float*)d_in[2];
    const float* w_bo = (const float*)d_in[3];
    const float* b_bo = (const float*)d_in[4];
    const float* w_co = (const float*)d_in[5];
    const float* b_co = (const float*)d_in[6];
    const float* w_bw = (const float*)d_in[7];
    const float* b_bw = (const float*)d_in[8];
    const float* w_cw = (const float*)d_in[9];
    const float* b_cw = (const float*)d_in[10];
    float* out = (float*)d_out;

    pd_kernel<<<ROWS, 128, 0, stream>>>(
        pro, feat, sp, w_bo, b_bo, w_co, b_co, w_bw, b_bw, w_cw, b_cw, out);
}

// Round 12
// 32.843 us; speedup vs baseline: 1.0833x; 1.0226x over previous
//
#include <hip/hip_runtime.h>
#include <hip/hip_bf16.h>

#define NB   32      // batch N
#define NRR  48      // rows NR
#define TT   2048    // temporal length T
#define DD   256     // d_model
#define QQ   32      // query points
#define ROWS (NB * NRR)   // 1536 total rows
#define NXCD 8

typedef float f32x4 __attribute__((ext_vector_type(4)));

// R9 body, phased ACROSS TWO LAUNCHES (no in-kernel phase loop -> no VGPR
// inflation; R7/R8/R11 all died on that). Each launch covers 16 of the 32
// n-slices; block b -> xcd = b&7 gathers only from n = nbase + 2*xcd + g,
// so each XCD's live gather set is exactly 2 slices = 4 MiB = its L2.
// Launch A (nbase=0) and B (nbase=16) serialize on the stream.
// Inner structure = R9 verbatim: 128 thr / 2 independent waves, wave covers
// all 256 channels as f32x4, 16 dots via wave butterfly, 8 q per wave,
// single-q bursts of 8 clamped coefficient-masked saddr loads + sched_barrier,
// NT stores.
__global__ __launch_bounds__(128) void pd_kernel(
    const float* __restrict__ pro,     // (N, NR, D)
    const float* __restrict__ feat,    // (N, T, D)
    const float* __restrict__ sp,      // (N, NR, Q)
    const float* __restrict__ w_bo, const float* __restrict__ b_bo,
    const float* __restrict__ w_co, const float* __restrict__ b_co,
    const float* __restrict__ w_bw, const float* __restrict__ b_bw,
    const float* __restrict__ w_cw, const float* __restrict__ b_cw,
    float* __restrict__ out,           // (Q, ROWS, D)
    int nbase)
{
    const int bid  = blockIdx.x;             // [0, 1536)
    const int xcd  = bid & (NXCD - 1);       // hardware XCD
    const int t    = bid >> 3;               // 0..191 within XCD
    const int half = t & 1;                  // which 16-q half of the row
    const int v2   = t >> 1;                 // 0..95
    const int g    = v2 / NRR;               // 0/1: slice within the XCD pair
    const int rr   = v2 % NRR;               // row within slice
    const int n    = nbase + 2 * xcd + g;    // this XCD's 2 live slices
    const int row  = n * NRR + rr;
    const int lane = threadIdx.x & 63;
    const int wv   = threadIdx.x >> 6;       // wave 0..1
    const int d4   = lane << 2;              // channel base (f32x4 per lane)
    const float inv_w = 1.0f / 2048.0f;

    // ---- 16 dot products of pro[row,:] with the 4x4 weight rows ----
    const f32x4 pv = *reinterpret_cast<const f32x4*>(pro + (size_t)row * DD + d4);

    float acc[16];
#pragma unroll
    for (int s = 0; s < 4; ++s) {
        f32x4 w;
        w = *reinterpret_cast<const f32x4*>(w_bo + s * DD + d4);
        acc[s]      = pv.x * w.x + pv.y * w.y + pv.z * w.z + pv.w * w.w;
        w = *reinterpret_cast<const f32x4*>(w_co + s * DD + d4);
        acc[4 + s]  = pv.x * w.x + pv.y * w.y + pv.z * w.z + pv.w * w.w;
        w = *reinterpret_cast<const f32x4*>(w_bw + s * DD + d4);
        acc[8 + s]  = pv.x * w.x + pv.y * w.y + pv.z * w.z + pv.w * w.w;
        w = *reinterpret_cast<const f32x4*>(w_cw + s * DD + d4);
        acc[12 + s] = pv.x * w.x + pv.y * w.y + pv.z * w.z + pv.w * w.w;
    }
    // 64-lane butterfly reduce; every lane ends with all 16 dot values.
#pragma unroll
    for (int st = 1; st < 64; st <<= 1) {
#pragma unroll
        for (int k = 0; k < 16; ++k)
            acc[k] += __shfl_xor(acc[k], st, 64);
    }

    float boff[4], coff[4], bw[4], cw[4];
#pragma unroll
    for (int s = 0; s < 4; ++s) {
        boff[s] = (acc[s]      + b_bo[s]) * inv_w;   // offset/WINDOW hoisted
        coff[s] = (acc[4 + s]  + b_co[s]) * inv_w;
        bw[s]   = acc[8 + s]  + b_bw[s];
        cw[s]   = acc[12 + s] + b_cw[s];
    }
    {   // softmax over s (max-subtracted), fold in the 0.5 row weight
        float mb = fmaxf(fmaxf(bw[0], bw[1]), fmaxf(bw[2], bw[3]));
        float mc = fmaxf(fmaxf(cw[0], cw[1]), fmaxf(cw[2], cw[3]));
        float sb = 0.f, sc = 0.f;
#pragma unroll
        for (int s = 0; s < 4; ++s) { bw[s] = expf(bw[s] - mb); sb += bw[s]; }
#pragma unroll
        for (int s = 0; s < 4; ++s) { cw[s] = expf(cw[s] - mc); sc += cw[s]; }
        const float rb = 0.5f / sb, rc = 0.5f / sc;
#pragma unroll
        for (int s = 0; s < 4; ++s) { bw[s] *= rb; cw[s] *= rc; }
    }

    // ---- gather + mix: this wave owns q = 16*half + 8*wv + j, j=0..7 ----
    const float* fnrow = feat + (size_t)n * (TT * DD);   // wave-uniform base
    const float* spr   = sp + (size_t)row * QQ;
    const int    qbase = (half << 4) + (wv << 3);

#pragma unroll
    for (int j = 0; j < 8; ++j) {
        const int   q     = qbase + j;
        const bool  isB   = (q < 4);             // wave-uniform
        const float point = spr[q];

        int   idx[8];
        float cc[8];
#pragma unroll
        for (int s = 0; s < 4; ++s) {
            const float off = isB ? boff[s] : coff[s];
            const float loc = fminf(fmaxf(point + off, 0.f), 1.f);
            const float px  = loc * (float)TT - 0.5f;
            const float x0f = floorf(px);
            const float w1  = px - x0f;          // right-neighbor weight
            const int   x0  = (int)x0f;          // in [-1, 2047]
            const int   x0c = x0 < 0 ? 0 : x0;
            const int   x1c = x0 + 1 > TT - 1 ? TT - 1 : x0 + 1;
            const float wgt = isB ? bw[s] : cw[s];
            cc[2 * s]     = (x0 >= 0)     ? wgt * (1.f - w1) : 0.f;
            cc[2 * s + 1] = (x0 + 1 < TT) ? wgt * w1         : 0.f;
            idx[2 * s]     = __builtin_amdgcn_readfirstlane(x0c) * DD;
            idx[2 * s + 1] = __builtin_amdgcn_readfirstlane(x1c) * DD;
        }

        f32x4 gv[8];
#pragma unroll
        for (int k = 0; k < 8; ++k)
            gv[k] = *reinterpret_cast<const f32x4*>(fnrow + idx[k] + d4);

        // Pin: all 8 loads issued before any consumer (MLP=8).
        __builtin_amdgcn_sched_barrier(0);

        f32x4 o = {0.f, 0.f, 0.f, 0.f};
#pragma unroll
        for (int k = 0; k < 8; ++k)
            o += cc[k] * gv[k];

        __builtin_nontemporal_store(o,
            reinterpret_cast<f32x4*>(out + ((size_t)q * ROWS + row) * DD + d4));
    }
}

extern "C" void kernel_launch(void* const* d_in, const int* in_sizes, int n_in,
                              void* d_out, int out_size, void* d_ws, size_t ws_size,
                              hipStream_t stream) {
    const float* pro  = (const float*)d_in[0];
    const float* feat = (const float*)d_in[1];
    const float* sp   = (const float*)d_in[2];
    const float* w_bo = (const float*)d_in[3];
    const float* b_bo = (const float*)d_in[4];
    const float* w_co = (const float*)d_in[5];
    const float* b_co = (const float*)d_in[6];
    const float* w_bw = (const float*)d_in[7];
    const float* b_bw = (const float*)d_in[8];
    const float* w_cw = (const float*)d_in[9];
    const float* b_cw = (const float*)d_in[10];
    float* out = (float*)d_out;

    // Phase A: n in [0,16) -- each XCD gathers from 2 slices (4 MiB, L2-fit).
    pd_kernel<<<ROWS, 128, 0, stream>>>(
        pro, feat, sp, w_bo, b_bo, w_co, b_co, w_bw, b_bw, w_cw, b_cw, out, 0);
    // Phase B: n in [16,32).
    pd_kernel<<<ROWS, 128, 0, stream>>>(
        pro, feat, sp, w_bo, b_bo, w_co, b_co, w_bw, b_bw, w_cw, b_cw, out, 16);
}

// Round 13
// 28.218 us; speedup vs baseline: 1.2608x; 1.1639x over previous
//
#include <hip/hip_runtime.h>
#include <hip/hip_bf16.h>

#define NB   32      // batch N
#define NRR  48      // rows NR
#define TT   2048    // temporal length T
#define DD   256     // d_model
#define QQ   32      // query points
#define ROWS (NB * NRR)   // 1536 total rows
#define NXCD 8

typedef float f32x4 __attribute__((ext_vector_type(4)));

// Best-measured configuration (R6: 28.2 us). One block per (n,r) row;
// 256 threads = 4 waves; wave wv owns q = 8*wv..8*wv+7. Gather indices are
// wave-uniform -> readfirstlane to SGPR (saddr-form loads). Query points in
// PAIRS: 16 clamped, coefficient-masked loads per burst; sched_barrier(0)
// pins all 16 in flight (MLP=16). XCD swizzle keeps each n-slice's blocks on
// one XCD; NT stores keep the 48 MB output stream out of L2.
// Plateau analysis (R4-R12): ~100 MB/replay compulsory HBM traffic, feature
// fetch is demand-driven random 64B gathers (~3 TB/s effective) -> ~27-29 us
// floor. MLP, occupancy, prefetch, and L2-phasing levers all exhausted.
__global__ __launch_bounds__(256) void pd_kernel(
    const float* __restrict__ pro,     // (N, NR, D)
    const float* __restrict__ feat,    // (N, T, D)
    const float* __restrict__ sp,      // (N, NR, Q)
    const float* __restrict__ w_bo, const float* __restrict__ b_bo,
    const float* __restrict__ w_co, const float* __restrict__ b_co,
    const float* __restrict__ w_bw, const float* __restrict__ b_bw,
    const float* __restrict__ w_cw, const float* __restrict__ b_cw,
    float* __restrict__ out)           // (Q, ROWS, D)
{
    const int bid = blockIdx.x;
    const int row = (bid & (NXCD - 1)) * (ROWS / NXCD) + (bid >> 3);
    const int n    = row / NRR;
    const int lane = threadIdx.x & 63;
    const int wv   = threadIdx.x >> 6;      // wave 0..3
    const int d4   = lane << 2;             // channel base (float4 per lane)
    const float inv_w = 1.0f / 2048.0f;

    // ---- 16 dot products of pro[row,:] with the 4x4 weight rows ----
    const f32x4 p = *reinterpret_cast<const f32x4*>(pro + (size_t)row * DD + d4);

    float acc[16];
#pragma unroll
    for (int s = 0; s < 4; ++s) {
        f32x4 w;
        w = *reinterpret_cast<const f32x4*>(w_bo + s * DD + d4);
        acc[s]      = p.x * w.x + p.y * w.y + p.z * w.z + p.w * w.w;
        w = *reinterpret_cast<const f32x4*>(w_co + s * DD + d4);
        acc[4 + s]  = p.x * w.x + p.y * w.y + p.z * w.z + p.w * w.w;
        w = *reinterpret_cast<const f32x4*>(w_bw + s * DD + d4);
        acc[8 + s]  = p.x * w.x + p.y * w.y + p.z * w.z + p.w * w.w;
        w = *reinterpret_cast<const f32x4*>(w_cw + s * DD + d4);
        acc[12 + s] = p.x * w.x + p.y * w.y + p.z * w.z + p.w * w.w;
    }
    // 64-lane butterfly reduce; every lane ends with the full dot values.
#pragma unroll
    for (int st = 1; st < 64; st <<= 1) {
#pragma unroll
        for (int k = 0; k < 16; ++k)
            acc[k] += __shfl_xor(acc[k], st, 64);
    }

    float boff[4], coff[4], bw[4], cw[4];
#pragma unroll
    for (int s = 0; s < 4; ++s) {
        boff[s] = (acc[s]      + b_bo[s]) * inv_w;   // offset/WINDOW hoisted
        coff[s] = (acc[4 + s]  + b_co[s]) * inv_w;
        bw[s]   = acc[8 + s]  + b_bw[s];
        cw[s]   = acc[12 + s] + b_cw[s];
    }
    // softmax over s (max-subtracted), fold in the 0.5 row weight.
    {
        float mb = fmaxf(fmaxf(bw[0], bw[1]), fmaxf(bw[2], bw[3]));
        float mc = fmaxf(fmaxf(cw[0], cw[1]), fmaxf(cw[2], cw[3]));
        float sb = 0.f, sc = 0.f;
#pragma unroll
        for (int s = 0; s < 4; ++s) { bw[s] = expf(bw[s] - mb); sb += bw[s]; }
#pragma unroll
        for (int s = 0; s < 4; ++s) { cw[s] = expf(cw[s] - mc); sc += cw[s]; }
        const float rb = 0.5f / sb, rc = 0.5f / sc;   // 0.5 = y=-1 row weight
#pragma unroll
        for (int s = 0; s < 4; ++s) { bw[s] *= rb; cw[s] *= rc; }
    }

    // ---- gather + mix: q-pairs, forced 16-load bursts ----
    const float* fnrow = feat + (size_t)n * (TT * DD);   // wave-uniform base
    const float* spr   = sp + (size_t)row * QQ;

#pragma unroll
    for (int j2 = 0; j2 < 4; ++j2) {
        int   idx[16];
        float cc[16];
#pragma unroll
        for (int h = 0; h < 2; ++h) {
            const int   q     = (wv << 3) + (j2 << 1) + h;
            const bool  isB   = (q < 4);             // wave-uniform
            const float point = spr[q];
#pragma unroll
            for (int s = 0; s < 4; ++s) {
                const float off = isB ? boff[s] : coff[s];
                const float loc = fminf(fmaxf(point + off, 0.f), 1.f);
                const float px  = loc * (float)TT - 0.5f;
                const float x0f = floorf(px);
                const float w1  = px - x0f;          // right-neighbor weight
                const int   x0  = (int)x0f;          // in [-1, 2047]
                const int   x0c = x0 < 0 ? 0 : x0;
                const int   x1c = x0 + 1 > TT - 1 ? TT - 1 : x0 + 1;
                const float wgt = isB ? bw[s] : cw[s];
                const int   k   = (h << 3) + (s << 1);
                cc[k]     = (x0 >= 0)     ? wgt * (1.f - w1) : 0.f;
                cc[k + 1] = (x0 + 1 < TT) ? wgt * w1         : 0.f;
                idx[k]     = __builtin_amdgcn_readfirstlane(x0c) * DD;
                idx[k + 1] = __builtin_amdgcn_readfirstlane(x1c) * DD;
            }
        }

        f32x4 gv[16];
#pragma unroll
        for (int k = 0; k < 16; ++k)
            gv[k] = *reinterpret_cast<const f32x4*>(fnrow + idx[k] + d4);

        // Pin the schedule: all 16 loads issued before any consumer.
        __builtin_amdgcn_sched_barrier(0);

        f32x4 o0 = {0.f, 0.f, 0.f, 0.f};
        f32x4 o1 = {0.f, 0.f, 0.f, 0.f};
#pragma unroll
        for (int k = 0; k < 8; ++k)  o0 += cc[k] * gv[k];
#pragma unroll
        for (int k = 8; k < 16; ++k) o1 += cc[k] * gv[k];

        const int q0 = (wv << 3) + (j2 << 1);
        __builtin_nontemporal_store(o0,
            reinterpret_cast<f32x4*>(out + ((size_t)q0 * ROWS + row) * DD + d4));
        __builtin_nontemporal_store(o1,
            reinterpret_cast<f32x4*>(out + ((size_t)(q0 + 1) * ROWS + row) * DD + d4));
    }
}

extern "C" void kernel_launch(void* const* d_in, const int* in_sizes, int n_in,
                              void* d_out, int out_size, void* d_ws, size_t ws_size,
                              hipStream_t stream) {
    const float* pro  = (const float*)d_in[0];
    const float* feat = (const float*)d_in[1];
    const float* sp   = (const float*)d_in[2];
    const float* w_bo = (const float*)d_in[3];
    const float* b_bo = (const float*)d_in[4];
    const float* w_co = (const float*)d_in[5];
    const float* b_co = (const float*)d_in[6];
    const float* w_bw = (const float*)d_in[7];
    const float* b_bw = (const float*)d_in[8];
    const float* w_cw = (const float*)d_in[9];
    const float* b_cw = (const float*)d_in[10];
    float* out = (float*)d_out;

    pd_kernel<<<ROWS, 256, 0, stream>>>(
        pro, feat, sp, w_bo, b_bo, w_co, b_co, w_bw, b_bw, w_cw, b_cw, out);
}